// Round 15
// baseline (140.101 us; speedup 1.0000x reference)
//
#include <hip/hip_runtime.h>
#include <cstdint>

#define HW 200704      // 448*448
#define IMG_W 448
#define NCLS 20
#define NDIM 256
#define NB2 784        // cam tiles per batch (256 px each)
#define LK 260         // padded LDS stride: float4-aligned

// async global->LDS DMA, 4B per lane, dest = wave-uniform base + lane*4
#define ASYNC_COPY4(gp, lp)                                                    \
  __builtin_amdgcn_global_load_lds(                                            \
      (const __attribute__((address_space(1))) void*)(gp),                     \
      (__attribute__((address_space(3))) void*)(lp), 4, 0, 0)

// ---------------------------------------------------------------------------
// K1: fused [pseudo | transpose] (r14, unchanged). Pseudo is barrier-free:
// per-wave present-mask ballot, per-wave DMAs + s_waitcnt, own-column consume.
__global__ __launch_bounds__(256) void k_front(const float* __restrict__ fmap,
                                               float* __restrict__ fmapT,
                                               const float* __restrict__ cam,
                                               const float* __restrict__ cls_label,
                                               const float* __restrict__ hig_p,
                                               const float* __restrict__ low_p,
                                               const float* __restrict__ bg_p,
                                               float* __restrict__ W) {
  __shared__ float sT[NCLS][256];
  int tid = threadIdx.x;

  if (blockIdx.x >= 2 * NB2) {
    float (*tile)[33] = (float (*)[33]) & sT[0][0];
    int blk = blockIdx.x - 2 * NB2;
    int b = blk / 200;
    int t = blk % 200;
    int dT = t / 25, sT2 = t % 25;
    int ty = tid >> 5, tx = tid & 31;
#pragma unroll
    for (int r = 0; r < 4; ++r) {
      int d = dT * 32 + ty + r * 8;
      int s = sT2 * 32 + tx;
      if (s < 784) tile[ty + r * 8][tx] = fmap[((size_t)(b * 256 + d)) * 784 + s];
    }
    __syncthreads();
#pragma unroll
    for (int r = 0; r < 4; ++r) {
      int s = sT2 * 32 + ty + r * 8;
      int d = dT * 32 + tx;
      if (s < 784) fmapT[((size_t)(b * 784 + s)) * 256 + d] = tile[tx][ty + r * 8];
    }
    return;
  }

  int b = blockIdx.x / NB2;
  int blkInB = blockIdx.x % NB2;
  int pix0 = blkInB * 256;
  int wave = tid >> 6, lane = tid & 63;

  bool pres = (lane < NCLS) && (cls_label[b * NCLS + lane] != 0.0f);
  unsigned long long pm = __ballot(pres);
  unsigned mask = (unsigned)(pm & 0xFFFFFu);
  int np = __popc(mask);
  const float* camb = cam + (size_t)b * NCLS * HW + pix0 + wave * 64 + lane;

  {
    unsigned m = mask;
    for (int k = 0; k < np; ++k) {
      int c = __builtin_ctz(m); m &= m - 1u;
      ASYNC_COPY4(camb + (size_t)c * HW, &sT[k][wave * 64]);
    }
  }
  __builtin_amdgcn_s_waitcnt(0);       // per-wave drain

  float top1 = -1.0f, sec = -1.0f;
  int cls1 = 0;
  {
    unsigned m = mask;
    for (int k = 0; k < np; ++k) {
      int c = __builtin_ctz(m); m &= m - 1u;
      float x = sT[k][tid];
      bool gt = x > top1;
      sec = gt ? top1 : fmaxf(sec, fminf(x, top1));
      cls1 = gt ? c : cls1;
      top1 = gt ? x : top1;
    }
  }
  if (np < NCLS) sec = fmaxf(sec, 0.0f);
  float hig = hig_p[0], low = low_p[0], bg = bg_p[0];
  int pix = pix0 + tid;
  int ps = cls1 + 1;
  if (top1 < hig) ps = 255;
  if (top1 < low) ps = 0;
  if (top1 < bg)  ps = 0;
  if ((top1 - sec < 0.3f) && (top1 > hig)) ps = 255;
  if (ps >= 1 && ps <= NCLS) {
    int cls = ps - 1;
    int y = pix / IMG_W, x = pix % IMG_W;
    float sy = (y + 0.5f) * 0.0625f - 0.5f; sy = fminf(fmaxf(sy, 0.0f), 27.0f);
    float sx = (x + 0.5f) * 0.0625f - 0.5f; sx = fminf(fmaxf(sx, 0.0f), 27.0f);
    int fy0 = (int)sy, fx0 = (int)sx;
    int fy1 = min(fy0 + 1, 27), fx1 = min(fx0 + 1, 27);
    float wy = sy - (float)fy0, wx = sx - (float)fx0;
    float* Wb = W + (size_t)(b * NCLS + cls) * 784;
    atomicAdd(&Wb[fy0 * 28 + fx0], (1.0f - wy) * (1.0f - wx));
    atomicAdd(&Wb[fy0 * 28 + fx1], (1.0f - wy) * wx);
    atomicAdd(&Wb[fy1 * 28 + fx0], wy * (1.0f - wx));
    atomicAdd(&Wb[fy1 * 28 + fx1], wy * wx);
  }
}

// ---------------------------------------------------------------------------
// K2: fused [features split-K | loss]. grid = 160 x 1024. Feat: bc=blk>>2,
// part=blk&3, h=tid>>8 owns accumulator a_h -> combine (H0+H1)+(H2+H3) ==
// r14's (a0+a1)+(a2+a3) tree bit-for-bit. ALL blocks reach the ticket; the
// 160th runs the loss (r14 k_loss verbatim).
__global__ __launch_bounds__(1024) void k_feat_loss(const float* __restrict__ fmapT,
                                                    const float* __restrict__ cam,
                                                    const float* __restrict__ Wg,
                                                    const float* __restrict__ cls_label,
                                                    const float* __restrict__ proj_w,
                                                    const float* __restrict__ fc_init,
                                                    int* __restrict__ done,
                                                    float* __restrict__ P,
                                                    float* __restrict__ S,
                                                    float* __restrict__ cntW,
                                                    float* __restrict__ out) {
  // feat scratch
  __shared__ float sW[784];
  __shared__ float sH[4][256];
  __shared__ float sRed[16];
  __shared__ float sCntf;
  __shared__ float wv[16]; __shared__ int wi[16];
  __shared__ float selV; __shared__ int selI;
  __shared__ int sTop[25];
  __shared__ int sLast;
  // loss state
  __shared__ float sFsm[2][NCLS * LK];
  __shared__ float sFc[NCLS * LK], sPw[NCLS * LK];
  __shared__ float sLogit[2][400], sCos[400];
  __shared__ float sBCE[2][NCLS], sRow[NCLS];
  __shared__ float sNormI[2][NCLS], sNormC[NCLS];
  __shared__ int   sZI[2][NCLS], sZC[NCLS], sQual[NCLS];
  __shared__ float sPres[2][NCLS];
  __shared__ float sScal[2];

  int bc = blockIdx.x >> 2, part = blockIdx.x & 3;
  int b = bc / NCLS;
  int tid = threadIdx.x;
  int dim = tid & 255, h = tid >> 8;

  if (cls_label[bc] != 0.0f) {
    for (int s = tid; s < 784; s += 1024) sW[s] = Wg[(size_t)bc * 784 + s];
    __syncthreads();
    // cnt = sum(W row); non-negative -> ==0 exact
    {
      float cs = (tid < 784) ? sW[tid] : 0.0f;
      for (int off = 32; off > 0; off >>= 1) cs += __shfl_xor(cs, off, 64);
      if ((tid & 63) == 0) sRed[tid >> 6] = cs;
      __syncthreads();
      if (tid == 0) {
        float s = 0.0f;
        for (int w = 0; w < 16; ++w) s += sRed[w];
        sCntf = s;
      }
      __syncthreads();
    }
    float cntf = sCntf;
    const float* fT = fmapT + (size_t)b * 784 * 256;

    if (cntf > 0.0f) {
      int s0 = part * 196;
      float a = 0.0f;
      for (int s = s0 + h; s < s0 + 196; s += 4)
        a += sW[s] * fT[(size_t)s * 256 + dim];
      sH[h][dim] = a;
      __syncthreads();
      if (tid < 256)
        P[(size_t)(bc * 4 + part) * 256 + tid] =
            (sH[0][tid] + sH[1][tid]) + (sH[2][tid] + sH[3][tid]);
      if (part == 0 && tid == 0) cntW[bc] = cntf;
    } else if (part == 0) {
      // exact top-25 (JAX tie-break) by full scan; statistically never taken
      if (tid == 0) cntW[bc] = 0.0f;
      const float* camc = cam + (size_t)bc * HW;
      float lastV = 3.0e38f; int lastI = -1;
      for (int r = 0; r < 25; ++r) {
        float bv = -1.0e30f; int bi = 0x7fffffff;
        for (int p = tid; p < HW; p += 1024) {
          float vv2 = camc[p];
          if (((vv2 < lastV) || (vv2 == lastV && p > lastI)) &&
              ((vv2 > bv) || (vv2 == bv && p < bi))) { bv = vv2; bi = p; }
        }
        for (int off = 32; off > 0; off >>= 1) {
          float ov = __shfl_xor(bv, off, 64);
          int   oi = __shfl_xor(bi, off, 64);
          if (ov > bv || (ov == bv && oi < bi)) { bv = ov; bi = oi; }
        }
        if ((tid & 63) == 0) { wv[tid >> 6] = bv; wi[tid >> 6] = bi; }
        __syncthreads();
        if (tid == 0) {
          for (int w = 1; w < 16; ++w)
            if (wv[w] > bv || (wv[w] == bv && wi[w] < bi)) { bv = wv[w]; bi = wi[w]; }
          selV = bv; selI = bi; sTop[r] = bi;
        }
        __syncthreads();
        lastV = selV; lastI = selI;
      }
      if (tid < 256) {
        float at = 0.0f;
        for (int r = 0; r < 25; ++r) {
          int p = sTop[r];
          int y = p / IMG_W, x = p % IMG_W;
          float sy = (y + 0.5f) * 0.0625f - 0.5f; sy = fminf(fmaxf(sy, 0.0f), 27.0f);
          float sx = (x + 0.5f) * 0.0625f - 0.5f; sx = fminf(fmaxf(sx, 0.0f), 27.0f);
          int fy0 = (int)sy, fx0 = (int)sx;
          int fy1 = min(fy0 + 1, 27), fx1 = min(fx0 + 1, 27);
          float wy = sy - (float)fy0, wx = sx - (float)fx0;
          at += (1.0f - wy) * (1.0f - wx) * fT[(size_t)(fy0 * 28 + fx0) * 256 + tid]
              + (1.0f - wy) * wx          * fT[(size_t)(fy0 * 28 + fx1) * 256 + tid]
              + wy          * (1.0f - wx) * fT[(size_t)(fy1 * 28 + fx0) * 256 + tid]
              + wy          * wx          * fT[(size_t)(fy1 * 28 + fx1) * 256 + tid];
        }
        S[(size_t)bc * 256 + tid] = at * (1.0f / 25.0f);
      }
    }
  }
  __syncthreads();
  // ---- last-block ticket (r12-proven device-scope release/acquire) ----
  if (tid == 0) {
    __threadfence();
    int t = atomicAdd(done, 1);
    sLast = (t == 159) ? 1 : 0;
  }
  __syncthreads();
  if (!sLast) return;
  __threadfence();

  // ================= loss (r14 k_loss, verbatim) ===========================
  for (int idx = tid; idx < 2 * NCLS * NDIM; idx += 1024) {
    int bcc = idx >> 8, d = idx & 255;
    float v = 0.0f;
    if (cls_label[bcc] != 0.0f) {
      float c = cntW[bcc];
      if (c > 0.0f) {
        const float* p = P + (size_t)bcc * 1024 + d;
        v = ((p[0] + p[256]) + (p[512] + p[768])) / fmaxf(c, 1.0f);
      } else {
        v = S[(size_t)bcc * 256 + d];
      }
    }
    sFsm[bcc / NCLS][(bcc % NCLS) * LK + d] = v;
  }
  for (int idx = tid; idx < NCLS * NDIM; idx += 1024) {
    int r = idx >> 8, d = idx & 255;
    sFc[r * LK + d] = fc_init[idx];
    sPw[r * LK + d] = proj_w[idx];
  }
  if (tid < 40) sPres[tid / NCLS][tid % NCLS] = cls_label[tid];
  if (tid == 0) { sScal[0] = 0.0f; sScal[1] = 0.0f; }
  __syncthreads();

  // P1: logits for both batches (zero fsm row -> exact 0 dot)
  if (tid < 800) {
    int bb = tid / 400, pi = tid % 400;
    int i = pi / NCLS, j = pi % NCLS;
    const float* ra = &sFsm[bb][i * LK];
    const float* rb = &sPw[j * LK];
    float a0 = 0, a1 = 0, a2 = 0, a3 = 0, a4 = 0, a5 = 0, a6 = 0, a7 = 0;
    for (int d = 0; d < 256; d += 16) {
      float4 x0 = *(const float4*)&ra[d],      y0 = *(const float4*)&rb[d];
      float4 x1 = *(const float4*)&ra[d + 4],  y1 = *(const float4*)&rb[d + 4];
      float4 x2 = *(const float4*)&ra[d + 8],  y2 = *(const float4*)&rb[d + 8];
      float4 x3 = *(const float4*)&ra[d + 12], y3 = *(const float4*)&rb[d + 12];
      a0 += x0.x * y0.x + x0.y * y0.y;  a1 += x0.z * y0.z + x0.w * y0.w;
      a2 += x1.x * y1.x + x1.y * y1.y;  a3 += x1.z * y1.z + x1.w * y1.w;
      a4 += x2.x * y2.x + x2.y * y2.y;  a5 += x2.z * y2.z + x2.w * y2.w;
      a6 += x3.x * y3.x + x3.y * y3.y;  a7 += x3.z * y3.z + x3.w * y3.w;
    }
    sLogit[bb][pi] = ((a0 + a1) + (a2 + a3)) + ((a4 + a5) + (a6 + a7));
  }
  __syncthreads();

  // P2: norms — 40 fsm rows + 20 fc_init rows
  {
    int g = tid >> 3, sub = tid & 7;
    if (g < 60) {
      const float* row = (g < 40) ? &sFsm[g / NCLS][(g % NCLS) * LK] : &sFc[(g - 40) * LK];
      float a0 = 0.0f, a1 = 0.0f, a2 = 0.0f, a3 = 0.0f;
      int d0 = sub * 32;
#pragma unroll
      for (int d = d0; d < d0 + 32; d += 8) {
        float4 x = *(const float4*)&row[d];
        float4 y = *(const float4*)&row[d + 4];
        a0 += x.x * x.x + x.y * x.y;
        a1 += x.z * x.z + x.w * x.w;
        a2 += y.x * y.x + y.y * y.y;
        a3 += y.z * y.z + y.w * y.w;
      }
      float s = (a0 + a1) + (a2 + a3);
      s += __shfl_xor(s, 1, 64);
      s += __shfl_xor(s, 2, 64);
      s += __shfl_xor(s, 4, 64);
      if (sub == 0) {
        if (g < 40) { sNormI[g / NCLS][g % NCLS] = fmaxf(sqrtf(s), 1e-12f); sZI[g / NCLS][g % NCLS] = (s == 0.0f); }
        else { sNormC[g - 40] = fmaxf(sqrtf(s), 1e-12f); sZC[g - 40] = (s == 0.0f); }
      }
    }
  }
  __syncthreads();

  // P3: BCE rows for both batches
  {
    int team = tid >> 5, jj = tid & 31;
    for (int r = team; r < 40; r += 32) {
      int bb = r / NCLS, i = r % NCLS;
      float l = (jj < NCLS) ? sLogit[bb][i * NCLS + jj] : -3.0e38f;
      float m = l;
#pragma unroll
      for (int off = 1; off < 32; off <<= 1) m = fmaxf(m, __shfl_xor(m, off, 64));
      float e = (jj < NCLS) ? expf(l - m) : 0.0f;
      float sS = e;
#pragma unroll
      for (int off = 1; off < 32; off <<= 1) sS += __shfl_xor(sS, off, 64);
      float term = 0.0f;
      if (jj < NCLS) {
        float p = e / sS;
        term = (jj == i) ? fmaxf(logf(p), -100.0f) : fmaxf(log1pf(-p), -100.0f);
      }
#pragma unroll
      for (int off = 1; off < 32; off <<= 1) term += __shfl_xor(term, off, 64);
      if (jj == 0) sBCE[bb][i] = -term / 20.0f;
    }
  }
  __syncthreads();

  // sequential over batches
  for (int bb = 0; bb < 2; ++bb) {
    if (bb == 1) {
      int g = tid >> 3, sub = tid & 7;
      if (g < NCLS) {
        const float* row = &sFc[g * LK];
        float a0 = 0.0f, a1 = 0.0f, a2 = 0.0f, a3 = 0.0f;
        int d0 = sub * 32;
#pragma unroll
        for (int d = d0; d < d0 + 32; d += 8) {
          float4 x = *(const float4*)&row[d];
          float4 y = *(const float4*)&row[d + 4];
          a0 += x.x * x.x + x.y * x.y;
          a1 += x.z * x.z + x.w * x.w;
          a2 += y.x * y.x + y.y * y.y;
          a3 += y.z * y.z + y.w * y.w;
        }
        float s = (a0 + a1) + (a2 + a3);
        s += __shfl_xor(s, 1, 64);
        s += __shfl_xor(s, 2, 64);
        s += __shfl_xor(s, 4, 64);
        if (sub == 0) { sNormC[g] = fmaxf(sqrtf(s), 1e-12f); sZC[g] = (s == 0.0f); }
      }
      __syncthreads();
    }
    {
      int pair = tid >> 1, sub = tid & 1;
      if (pair < 400) {
        int i = pair / NCLS, j = pair % NCLS;
        float c0;
        if (sZI[bb][i] || sZC[j]) c0 = 0.0f;
        else {
          const float* ra = &sFsm[bb][i * LK];
          const float* rb = &sFc[j * LK];
          float a0 = 0.0f, a1 = 0.0f, a2 = 0.0f, a3 = 0.0f;
          int d0 = sub * 128;
          for (int d = d0; d < d0 + 128; d += 8) {
            float4 x  = *(const float4*)&ra[d];
            float4 y  = *(const float4*)&rb[d];
            float4 x2 = *(const float4*)&ra[d + 4];
            float4 y2 = *(const float4*)&rb[d + 4];
            a0 += x.x * y.x + x.y * y.y;
            a1 += x.z * y.z + x.w * y.w;
            a2 += x2.x * y2.x + x2.y * y2.y;
            a3 += x2.z * y2.z + x2.w * y2.w;
          }
          float acc = (a0 + a1) + (a2 + a3);
          acc += __shfl_xor(acc, 1, 64);
          c0 = fabsf(acc / (sNormI[bb][i] * sNormC[j]));
        }
        if (sub == 0) sCos[pair] = fminf(fmaxf(c0, 1e-5f), 1.0f - 1e-5f);
      }
    }
    __syncthreads();
    {
      int i = tid >> 5, jj = tid & 31;
      if (i < NCLS) {
        float pres = (sPres[bb][i] > 0.5f) ? 1.0f : 0.0f;
        float contrib = 0.0f, omv = -3.0e38f;
        if (jj < NCLS) {
          float c0 = sCos[i * NCLS + jj];
          float ident = (jj == i) ? pres : 0.0f;
          contrib = ident * logf(c0) + (1.0f - ident) * log1pf(-c0);
          if (jj != i) omv = c0;
        }
#pragma unroll
        for (int off = 1; off < 32; off <<= 1) {
          contrib += __shfl_xor(contrib, off, 64);
          omv = fmaxf(omv, __shfl_xor(omv, off, 64));
        }
        if (jj == 0) { sRow[i] = contrib; sQual[i] = (pres > 0.5f && omv < 0.6f) ? 1 : 0; }
      }
    }
    __syncthreads();
    if (tid == 0) {
      float s = 0.0f;
      for (int r = 0; r < NCLS; ++r) s += sRow[r];
      sScal[0] -= s / 400.0f;
      float add = 0.0f; int nq = 0;
      for (int r = 0; r < NCLS; ++r) if (sQual[r]) { add += sBCE[bb][r]; nq++; }
      float lc = sScal[1] + add;
      if (nq > 0) lc = lc / fmaxf((float)nq, 1.0f);
      sScal[1] = lc;
    }
    for (int idx = tid; idx < NCLS * NDIM; idx += 1024) {
      int r = idx >> 8, d = idx & 255;
      if (sQual[r]) sFc[r * LK + d] = 0.95f * sFc[r * LK + d] + 0.05f * sFsm[bb][r * LK + d];
    }
    __syncthreads();
  }
  if (tid == 0) out[0] = sScal[0] + sScal[1];
}

// ---------------------------------------------------------------------------
extern "C" void kernel_launch(void* const* d_in, const int* in_sizes, int n_in,
                              void* d_out, int out_size, void* d_ws, size_t ws_size,
                              hipStream_t stream) {
  const float* fmap      = (const float*)d_in[0];
  const float* cam       = (const float*)d_in[1];
  const float* cls_label = (const float*)d_in[2];
  const float* proj_w    = (const float*)d_in[3];
  const float* fc_init   = (const float*)d_in[4];
  const float* hig       = (const float*)d_in[5];
  const float* low       = (const float*)d_in[6];
  const float* bg        = (const float*)d_in[7];
  float* out = (float*)d_out;

  char* ws = (char*)d_ws;
  float* W     = (float*)(ws);                 // 125440 B
  int*   done  = (int*)  (ws + 125440);        // 32 B
  float* cntW  = (float*)(ws + 125472);        // 160 B
  float* P     = (float*)(ws + 125632);        // 40*4*256*4 = 163840 B
  float* S     = (float*)(ws + 289472);        // 40*256*4   = 40960 B
  float* fmapT = (float*)(ws + 330432);        // 1605632 B

  hipMemsetAsync(ws, 0, 125472, stream);       // zero W + done
  k_front    <<<2 * NB2 + 400,  256, 0, stream>>>(fmap, fmapT, cam, cls_label,
                                                  hig, low, bg, W);
  k_feat_loss<<<          160, 1024, 0, stream>>>(fmapT, cam, W, cls_label,
                                                  proj_w, fc_init, done, P, S, cntW, out);
}